// Round 1
// baseline (1035.184 us; speedup 1.0000x reference)
//
#include <hip/hip_runtime.h>
#include <cstdint>
#include <cstddef>

// Problem constants (from reference): E=8, H=2048, I=1408, T=16384
#define TT 16384
#define HH 2048
#define II 1408
#define EE 8

typedef __attribute__((ext_vector_type(4))) float f32x4;
typedef __attribute__((ext_vector_type(8))) short bf16x8;  // 8 bf16 (4 VGPRs)
typedef __attribute__((ext_vector_type(4))) short s16x4;
typedef __attribute__((ext_vector_type(8))) short s16x8;

__device__ __forceinline__ short f2bf(float f) {
  // round-to-nearest-even fp32 -> bf16 (matches jnp astype)
  union { float f; unsigned u; } v; v.f = f;
  unsigned u = v.u;
  return (short)((u + 0x7fffu + ((u >> 16) & 1u)) >> 16);
}
__device__ __forceinline__ float bf2f(short s) {
  union { unsigned u; float f; } v;
  v.u = ((unsigned)(unsigned short)s) << 16;
  return v.f;
}

// Map linear M-tile id -> (expert, row_base, rows_valid) for BM=128 ragged tiles.
__device__ __forceinline__ void find_tile(const int* __restrict__ counts, int mt,
                                          int& e_out, int& row_base, int& rows_valid) {
  int off = 0, acc = 0, e = -1, rb = 0, rv = 0;
#pragma unroll
  for (int ee = 0; ee < EE; ++ee) {
    int n = counts[ee];
    int tiles = (n + 127) >> 7;
    if (e < 0 && mt < acc + tiles) {
      e = ee;
      int lmt = mt - acc;
      rb = off + (lmt << 7);
      rv = n - (lmt << 7);
      rv = rv > 128 ? 128 : rv;
    }
    acc += tiles;
    off += n;
  }
  e_out = e; row_base = rb; rows_valid = rv;
}

// GEMM1 + SiLU-gate fusion.
// C_gate[t, j] = sum_h x[t,h]*gup[e, j, h];  C_up at j + II.
// Block: 128 token rows x 64 i-cols (gate AND up halves). 4 waves (2x2), each
// wave: 64 rows x 32 cols of gate + same of up. BK=32.
__global__ __launch_bounds__(256, 2)
void moe_gemm1(const float* __restrict__ x, const float* __restrict__ gup,
               const int* __restrict__ counts, short* __restrict__ h) {
  __shared__ short As[128][32];
  __shared__ short Bg[64][32];
  __shared__ short Bu[64][32];

  const int tid  = threadIdx.x;
  const int lane = tid & 63;
  const int wid  = tid >> 6;
  const int wr   = wid >> 1;  // 0..1
  const int wc   = wid & 1;   // 0..1

  int e, row_base, rows_valid;
  find_tile(counts, blockIdx.x, e, row_base, rows_valid);
  if (e < 0 || rows_valid <= 0) return;

  const int nt = blockIdx.y;           // 0..21 over I/64
  const size_t wbase = (size_t)e * (2 * II) * HH;
  const int jg = nt * 64;              // gate row (out col) base in weights
  const int ju = II + nt * 64;         // up half

  f32x4 a_st[4], bg_st[2], bu_st[2];

  auto load_tiles = [&](int kb) {
#pragma unroll
    for (int i = 0; i < 4; ++i) {
      int q = tid + 256 * i;
      int r = q >> 3, kq = q & 7;
      int gr = row_base + ((r < rows_valid) ? r : 0);  // clamp inside segment
      a_st[i] = *reinterpret_cast<const f32x4*>(&x[(size_t)gr * HH + kb + kq * 4]);
    }
#pragma unroll
    for (int i = 0; i < 2; ++i) {
      int q = tid + 256 * i;
      int r = q >> 3, kq = q & 7;
      bg_st[i] = *reinterpret_cast<const f32x4*>(&gup[wbase + (size_t)(jg + r) * HH + kb + kq * 4]);
      bu_st[i] = *reinterpret_cast<const f32x4*>(&gup[wbase + (size_t)(ju + r) * HH + kb + kq * 4]);
    }
  };

  auto write_tiles = [&]() {
#pragma unroll
    for (int i = 0; i < 4; ++i) {
      int q = tid + 256 * i;
      int r = q >> 3, kq = q & 7;
      s16x4 p;
      p[0] = f2bf(a_st[i][0]); p[1] = f2bf(a_st[i][1]);
      p[2] = f2bf(a_st[i][2]); p[3] = f2bf(a_st[i][3]);
      *reinterpret_cast<s16x4*>(&As[r][kq * 4]) = p;
    }
#pragma unroll
    for (int i = 0; i < 2; ++i) {
      int q = tid + 256 * i;
      int r = q >> 3, kq = q & 7;
      s16x4 pg, pu;
      pg[0] = f2bf(bg_st[i][0]); pg[1] = f2bf(bg_st[i][1]);
      pg[2] = f2bf(bg_st[i][2]); pg[3] = f2bf(bg_st[i][3]);
      pu[0] = f2bf(bu_st[i][0]); pu[1] = f2bf(bu_st[i][1]);
      pu[2] = f2bf(bu_st[i][2]); pu[3] = f2bf(bu_st[i][3]);
      *reinterpret_cast<s16x4*>(&Bg[r][kq * 4]) = pg;
      *reinterpret_cast<s16x4*>(&Bu[r][kq * 4]) = pu;
    }
  };

  f32x4 accg[4][2], accu[4][2];
  const f32x4 z = {0.f, 0.f, 0.f, 0.f};
#pragma unroll
  for (int m = 0; m < 4; ++m)
#pragma unroll
    for (int n = 0; n < 2; ++n) { accg[m][n] = z; accu[m][n] = z; }

  const int NK = HH / 32;  // 64
  load_tiles(0);
  for (int ks = 0; ks < NK; ++ks) {
    __syncthreads();           // previous compute finished with LDS
    write_tiles();
    if (ks + 1 < NK) load_tiles((ks + 1) * 32);  // prefetch next (overlaps MFMA)
    __syncthreads();           // tile ready

    bf16x8 a[4], bg[2], bu[2];
    const int ko = (lane >> 4) * 8;
    const int rl = lane & 15;
#pragma unroll
    for (int m = 0; m < 4; ++m)
      a[m] = *reinterpret_cast<const bf16x8*>(&As[wr * 64 + m * 16 + rl][ko]);
#pragma unroll
    for (int n = 0; n < 2; ++n) {
      bg[n] = *reinterpret_cast<const bf16x8*>(&Bg[wc * 32 + n * 16 + rl][ko]);
      bu[n] = *reinterpret_cast<const bf16x8*>(&Bu[wc * 32 + n * 16 + rl][ko]);
    }
#pragma unroll
    for (int m = 0; m < 4; ++m)
#pragma unroll
      for (int n = 0; n < 2; ++n) {
        accg[m][n] = __builtin_amdgcn_mfma_f32_16x16x32_bf16(a[m], bg[n], accg[m][n], 0, 0, 0);
        accu[m][n] = __builtin_amdgcn_mfma_f32_16x16x32_bf16(a[m], bu[n], accu[m][n], 0, 0, 0);
      }
  }

  // Epilogue: round to bf16 (ref: ragged_dot output is bf16), SiLU-gate, store h bf16.
  const int rl = lane & 15;
#pragma unroll
  for (int m = 0; m < 4; ++m) {
#pragma unroll
    for (int r = 0; r < 4; ++r) {
      int lr = wr * 64 + m * 16 + (lane >> 4) * 4 + r;
      if (lr < rows_valid) {
        size_t row = (size_t)(row_base + lr);
#pragma unroll
        for (int n = 0; n < 2; ++n) {
          float gf = bf2f(f2bf(accg[m][n][r]));
          float uf = bf2f(f2bf(accu[m][n][r]));
          float hv = gf / (1.0f + expf(-gf)) * uf;  // silu(g)*u in fp32
          h[row * II + jg + wc * 32 + n * 16 + rl] = f2bf(hv);
        }
      }
    }
  }
}

// GEMM2: out[t, n] = sum_i h[t,i] * dp[e, n, i].  Block: 128 rows x 128 cols,
// 4 waves (2x2), wave 64x64. BK=32, NK=44.
__global__ __launch_bounds__(256, 2)
void moe_gemm2(const short* __restrict__ h, const float* __restrict__ dp,
               const int* __restrict__ counts, float* __restrict__ out) {
  __shared__ short As[128][32];
  __shared__ short Bs[128][32];

  const int tid  = threadIdx.x;
  const int lane = tid & 63;
  const int wid  = tid >> 6;
  const int wr   = wid >> 1;
  const int wc   = wid & 1;

  int e, row_base, rows_valid;
  find_tile(counts, blockIdx.x, e, row_base, rows_valid);
  if (e < 0 || rows_valid <= 0) return;

  const int nb = blockIdx.y * 128;     // 0..15 over H/128
  const size_t wbase = (size_t)e * HH * II;

  s16x8 a_st[2];
  f32x4 b_st[4];

  auto load_tiles = [&](int kb) {
#pragma unroll
    for (int i = 0; i < 2; ++i) {
      int q = tid + 256 * i;
      int r = q >> 2, kh = q & 3;
      int gr = row_base + ((r < rows_valid) ? r : 0);
      a_st[i] = *reinterpret_cast<const s16x8*>(&h[(size_t)gr * II + kb + kh * 8]);
    }
#pragma unroll
    for (int i = 0; i < 4; ++i) {
      int q = tid + 256 * i;
      int r = q >> 3, kq = q & 7;
      b_st[i] = *reinterpret_cast<const f32x4*>(&dp[wbase + (size_t)(nb + r) * II + kb + kq * 4]);
    }
  };

  auto write_tiles = [&]() {
#pragma unroll
    for (int i = 0; i < 2; ++i) {
      int q = tid + 256 * i;
      int r = q >> 2, kh = q & 3;
      *reinterpret_cast<s16x8*>(&As[r][kh * 8]) = a_st[i];
    }
#pragma unroll
    for (int i = 0; i < 4; ++i) {
      int q = tid + 256 * i;
      int r = q >> 3, kq = q & 7;
      s16x4 p;
      p[0] = f2bf(b_st[i][0]); p[1] = f2bf(b_st[i][1]);
      p[2] = f2bf(b_st[i][2]); p[3] = f2bf(b_st[i][3]);
      *reinterpret_cast<s16x4*>(&Bs[r][kq * 4]) = p;
    }
  };

  f32x4 acc[4][4];
  const f32x4 z = {0.f, 0.f, 0.f, 0.f};
#pragma unroll
  for (int m = 0; m < 4; ++m)
#pragma unroll
    for (int n = 0; n < 4; ++n) acc[m][n] = z;

  const int NK = II / 32;  // 44
  load_tiles(0);
  for (int ks = 0; ks < NK; ++ks) {
    __syncthreads();
    write_tiles();
    if (ks + 1 < NK) load_tiles((ks + 1) * 32);
    __syncthreads();

    bf16x8 a[4], b[4];
    const int ko = (lane >> 4) * 8;
    const int rl = lane & 15;
#pragma unroll
    for (int m = 0; m < 4; ++m)
      a[m] = *reinterpret_cast<const bf16x8*>(&As[wr * 64 + m * 16 + rl][ko]);
#pragma unroll
    for (int n = 0; n < 4; ++n)
      b[n] = *reinterpret_cast<const bf16x8*>(&Bs[wc * 64 + n * 16 + rl][ko]);
#pragma unroll
    for (int m = 0; m < 4; ++m)
#pragma unroll
      for (int n = 0; n < 4; ++n)
        acc[m][n] = __builtin_amdgcn_mfma_f32_16x16x32_bf16(a[m], b[n], acc[m][n], 0, 0, 0);
  }

  const int rl = lane & 15;
#pragma unroll
  for (int m = 0; m < 4; ++m) {
#pragma unroll
    for (int r = 0; r < 4; ++r) {
      int lr = wr * 64 + m * 16 + (lane >> 4) * 4 + r;
      if (lr < rows_valid) {
        size_t row = (size_t)(row_base + lr);
#pragma unroll
        for (int n = 0; n < 4; ++n) {
          // ref: ragged_dot output bf16 -> astype f32: round to bf16 first
          out[row * HH + nb + wc * 64 + n * 16 + rl] = bf2f(f2bf(acc[m][n][r]));
        }
      }
    }
  }
}

extern "C" void kernel_launch(void* const* d_in, const int* in_sizes, int n_in,
                              void* d_out, int out_size, void* d_ws, size_t ws_size,
                              hipStream_t stream) {
  const float* x      = (const float*)d_in[0];
  const float* gup    = (const float*)d_in[1];
  const float* dp     = (const float*)d_in[2];
  const int*   counts = (const int*)d_in[3];
  float* out = (float*)d_out;
  short* h   = (short*)d_ws;  // bf16 h buffer: TT*II*2 = 46.1 MB

  // Worst-case ragged M-tiles: ceil(T/128) + E partial tiles = 136
  const int MT_MAX = (TT + 127) / 128 + EE;

  moe_gemm1<<<dim3(MT_MAX, II / 64), dim3(256), 0, stream>>>(x, gup, counts, h);
  moe_gemm2<<<dim3(MT_MAX, HH / 128), dim3(256), 0, stream>>>(h, dp, counts, out);
}

// Round 3
// 920.504 us; speedup vs baseline: 1.1246x; 1.1246x over previous
//
#include <hip/hip_runtime.h>
#include <cstdint>
#include <cstddef>

// Problem constants (from reference): E=8, H=2048, I=1408, T=16384
#define TT 16384
#define HH 2048
#define II 1408
#define EE 8

typedef __attribute__((ext_vector_type(4))) float f32x4;
typedef __attribute__((ext_vector_type(8))) short bf16x8;  // 8 bf16 (4 VGPRs)
typedef __attribute__((ext_vector_type(4))) short s16x4;
typedef __attribute__((ext_vector_type(8))) short s16x8;

__device__ __forceinline__ short f2bf(float f) {
  // round-to-nearest-even fp32 -> bf16 (matches jnp astype); epilogue-only
  union { float f; unsigned u; } v; v.f = f;
  unsigned u = v.u;
  return (short)((u + 0x7fffu + ((u >> 16) & 1u)) >> 16);
}
__device__ __forceinline__ float bf2f(short s) {
  union { unsigned u; float f; } v;
  v.u = ((unsigned)(unsigned short)s) << 16;
  return v.f;
}
// Hardware packed fp32->bf16 RNE convert: D.lo = cvt(lo), D.hi = cvt(hi)
__device__ __forceinline__ unsigned pk_bf16(float lo, float hi) {
  unsigned r;
  asm("v_cvt_pk_bf16_f32 %0, %1, %2" : "=v"(r) : "v"(lo), "v"(hi));
  return r;
}
__device__ __forceinline__ void cvt4(void* dst, const f32x4 v) {
  union { s16x4 s; unsigned u[2]; } p;
  p.u[0] = pk_bf16(v[0], v[1]);
  p.u[1] = pk_bf16(v[2], v[3]);
  *reinterpret_cast<s16x4*>(dst) = p.s;
}

// Map linear M-tile id -> (expert, row_base, rows_valid) for BM=128 ragged tiles.
__device__ __forceinline__ void find_tile(const int* __restrict__ counts, int mt,
                                          int& e_out, int& row_base, int& rows_valid) {
  int off = 0, acc = 0, e = -1, rb = 0, rv = 0;
#pragma unroll
  for (int ee = 0; ee < EE; ++ee) {
    int n = counts[ee];
    int tiles = (n + 127) >> 7;
    if (e < 0 && mt < acc + tiles) {
      e = ee;
      int lmt = mt - acc;
      rb = off + (lmt << 7);
      rv = n - (lmt << 7);
      rv = rv > 128 ? 128 : rv;
    }
    acc += tiles;
    off += n;
  }
  e_out = e; row_base = rb; rows_valid = rv;
}

// LDS tile geometry: logical [rows][32] bf16, stored as rows of 64B = 4 x 16B
// units, with unit index XOR-swizzled by (row&3). Frag reads (16 lanes reading
// 16 consecutive rows at one unit) then hit each bank-quad exactly 2x => free.
__device__ __forceinline__ int swz_off(int r, int kq) {
  // kq = 4-short (8B) column group 0..7; unit = kq>>1, half = kq&1
  return r * 64 + ((((kq >> 1) ^ (r & 3))) << 4) + ((kq & 1) << 3);
}

// ---------------------------------------------------------------------------
// GEMM1 + SiLU-gate fusion. Block: 128 token rows x (64 gate + 64 up) cols,
// 4 waves (2x2). BK=32, double-buffered LDS, 1 barrier/K-step, loads 2 ahead.
// ---------------------------------------------------------------------------
__global__ __launch_bounds__(256)
void moe_gemm1(const float* __restrict__ x, const float* __restrict__ gup,
               const int* __restrict__ counts, short* __restrict__ h) {
  __shared__ short As[2][128 * 32];
  __shared__ short Bg[2][64 * 32];
  __shared__ short Bu[2][64 * 32];

  const int tid  = threadIdx.x;
  const int lane = tid & 63;
  const int wid  = tid >> 6;
  const int wr   = wid >> 1;  // 0..1
  const int wc   = wid & 1;   // 0..1

  // N-fastest logical order + bijective XCD chunking (NB % 8 == 0)
  const int NT = II / 64;                        // 22
  const int NB = ((TT + 127) / 128 + EE) * NT;   // 2992
  const int l  = ((int)blockIdx.x % 8) * (NB / 8) + (int)blockIdx.x / 8;
  const int nt = l % NT;
  const int mt = l / NT;

  int e, row_base, rows_valid;
  find_tile(counts, mt, e, row_base, rows_valid);
  if (e < 0 || rows_valid <= 0) return;

  const size_t wbase = (size_t)e * (2 * II) * HH;
  const int jg = nt * 64;        // gate out-col base
  const int ju = II + nt * 64;   // up out-col base

  f32x4 a_st[4], bg_st[2], bu_st[2];

  auto load_tiles = [&](int kb) {
#pragma unroll
    for (int i = 0; i < 4; ++i) {
      int q = tid + 256 * i;
      int r = q >> 3, kq = q & 7;
      int gr = row_base + ((r < rows_valid) ? r : 0);
      a_st[i] = *reinterpret_cast<const f32x4*>(&x[(size_t)gr * HH + kb + kq * 4]);
    }
#pragma unroll
    for (int i = 0; i < 2; ++i) {
      int q = tid + 256 * i;
      int r = q >> 3, kq = q & 7;
      bg_st[i] = *reinterpret_cast<const f32x4*>(&gup[wbase + (size_t)(jg + r) * HH + kb + kq * 4]);
      bu_st[i] = *reinterpret_cast<const f32x4*>(&gup[wbase + (size_t)(ju + r) * HH + kb + kq * 4]);
    }
  };

  auto write_tiles = [&](int b) {
#pragma unroll
    for (int i = 0; i < 4; ++i) {
      int q = tid + 256 * i;
      int r = q >> 3, kq = q & 7;
      cvt4((char*)As[b] + swz_off(r, kq), a_st[i]);
    }
#pragma unroll
    for (int i = 0; i < 2; ++i) {
      int q = tid + 256 * i;
      int r = q >> 3, kq = q & 7;
      int off = swz_off(r, kq);
      cvt4((char*)Bg[b] + off, bg_st[i]);
      cvt4((char*)Bu[b] + off, bu_st[i]);
    }
  };

  f32x4 accg[4][2], accu[4][2];
  const f32x4 z = {0.f, 0.f, 0.f, 0.f};
#pragma unroll
  for (int m = 0; m < 4; ++m)
#pragma unroll
    for (int n = 0; n < 2; ++n) { accg[m][n] = z; accu[m][n] = z; }

  const int g  = lane >> 4;    // 0..3 : 16B k-unit
  const int rl = lane & 15;
  const int su = ((g ^ (rl & 3)) << 4);  // swizzled unit byte offset (row%16 == rl%16)

  const int NK = HH / 32;  // 64
  load_tiles(0);
  write_tiles(0);
  load_tiles(32);
  __syncthreads();

  int cur = 0;
  for (int ks = 0; ks < NK; ++ks) {
    bf16x8 a[4], bg[2], bu[2];
#pragma unroll
    for (int m = 0; m < 4; ++m)
      a[m] = *reinterpret_cast<const bf16x8*>((const char*)As[cur] + (wr * 64 + m * 16 + rl) * 64 + su);
#pragma unroll
    for (int n = 0; n < 2; ++n) {
      bg[n] = *reinterpret_cast<const bf16x8*>((const char*)Bg[cur] + (wc * 32 + n * 16 + rl) * 64 + su);
      bu[n] = *reinterpret_cast<const bf16x8*>((const char*)Bu[cur] + (wc * 32 + n * 16 + rl) * 64 + su);
    }
#pragma unroll
    for (int m = 0; m < 4; ++m)
#pragma unroll
      for (int n = 0; n < 2; ++n) {
        accg[m][n] = __builtin_amdgcn_mfma_f32_16x16x32_bf16(a[m], bg[n], accg[m][n], 0, 0, 0);
        accu[m][n] = __builtin_amdgcn_mfma_f32_16x16x32_bf16(a[m], bu[n], accu[m][n], 0, 0, 0);
      }
    if (ks + 1 < NK) {
      write_tiles(cur ^ 1);                 // tile ks+1 (loads issued 2 steps ago)
      if (ks + 2 < NK) load_tiles((ks + 2) * 32);
    }
    __syncthreads();
    cur ^= 1;
  }

  // Epilogue: round gate/up to bf16 (ref semantics), SiLU in fp32, store h bf16.
#pragma unroll
  for (int m = 0; m < 4; ++m) {
#pragma unroll
    for (int r = 0; r < 4; ++r) {
      int lr = wr * 64 + m * 16 + (lane >> 4) * 4 + r;
      if (lr < rows_valid) {
        size_t row = (size_t)(row_base + lr);
#pragma unroll
        for (int n = 0; n < 2; ++n) {
          float gf = bf2f(f2bf(accg[m][n][r]));
          float uf = bf2f(f2bf(accu[m][n][r]));
          float hv = gf / (1.0f + expf(-gf)) * uf;
          h[row * II + jg + wc * 32 + n * 16 + rl] = f2bf(hv);
        }
      }
    }
  }
}

// ---------------------------------------------------------------------------
// GEMM2: out[t, c] = sum_i h[t,i] * dp[e, c, i]. Block 128x128, 4 waves (2x2),
// BK=32, same dbuf/prefetch/swizzle structure.
// ---------------------------------------------------------------------------
__global__ __launch_bounds__(256)
void moe_gemm2(const short* __restrict__ h, const float* __restrict__ dp,
               const int* __restrict__ counts, float* __restrict__ out) {
  __shared__ short As[2][128 * 32];
  __shared__ short Bs[2][128 * 32];

  const int tid  = threadIdx.x;
  const int lane = tid & 63;
  const int wid  = tid >> 6;
  const int wr   = wid >> 1;
  const int wc   = wid & 1;

  const int NT = HH / 128;                       // 16
  const int NB = ((TT + 127) / 128 + EE) * NT;   // 2176
  const int l  = ((int)blockIdx.x % 8) * (NB / 8) + (int)blockIdx.x / 8;
  const int nt = l % NT;
  const int mt = l / NT;

  int e, row_base, rows_valid;
  find_tile(counts, mt, e, row_base, rows_valid);
  if (e < 0 || rows_valid <= 0) return;

  const int nb = nt * 128;
  const size_t wbase = (size_t)e * HH * II;

  s16x8 a_st[2];
  f32x4 b_st[4];

  auto load_tiles = [&](int kb) {
#pragma unroll
    for (int i = 0; i < 2; ++i) {
      int q = tid + 256 * i;
      int r = q >> 2, kh = q & 3;
      int gr = row_base + ((r < rows_valid) ? r : 0);
      a_st[i] = *reinterpret_cast<const s16x8*>(&h[(size_t)gr * II + kb + kh * 8]);
    }
#pragma unroll
    for (int i = 0; i < 4; ++i) {
      int q = tid + 256 * i;
      int r = q >> 3, kq = q & 7;
      b_st[i] = *reinterpret_cast<const f32x4*>(&dp[wbase + (size_t)(nb + r) * II + kb + kq * 4]);
    }
  };

  auto write_tiles = [&](int b) {
#pragma unroll
    for (int i = 0; i < 2; ++i) {
      int q = tid + 256 * i;
      int r = q >> 2, kh = q & 3;
      // 16B store at swizzled unit kh
      *reinterpret_cast<s16x8*>((char*)As[b] + r * 64 + ((kh ^ (r & 3)) << 4)) = a_st[i];
    }
#pragma unroll
    for (int i = 0; i < 4; ++i) {
      int q = tid + 256 * i;
      int r = q >> 3, kq = q & 7;
      cvt4((char*)Bs[b] + swz_off(r, kq), b_st[i]);
    }
  };

  f32x4 acc[4][4];
  const f32x4 z = {0.f, 0.f, 0.f, 0.f};
#pragma unroll
  for (int m = 0; m < 4; ++m)
#pragma unroll
    for (int n = 0; n < 4; ++n) acc[m][n] = z;

  const int g  = lane >> 4;
  const int rl = lane & 15;
  const int su = ((g ^ (rl & 3)) << 4);

  const int NK = II / 32;  // 44
  load_tiles(0);
  write_tiles(0);
  load_tiles(32);
  __syncthreads();

  int cur = 0;
  for (int ks = 0; ks < NK; ++ks) {
    bf16x8 a[4], b[4];
#pragma unroll
    for (int m = 0; m < 4; ++m)
      a[m] = *reinterpret_cast<const bf16x8*>((const char*)As[cur] + (wr * 64 + m * 16 + rl) * 64 + su);
#pragma unroll
    for (int n = 0; n < 4; ++n)
      b[n] = *reinterpret_cast<const bf16x8*>((const char*)Bs[cur] + (wc * 64 + n * 16 + rl) * 64 + su);
#pragma unroll
    for (int m = 0; m < 4; ++m)
#pragma unroll
      for (int n = 0; n < 4; ++n)
        acc[m][n] = __builtin_amdgcn_mfma_f32_16x16x32_bf16(a[m], b[n], acc[m][n], 0, 0, 0);
    if (ks + 1 < NK) {
      write_tiles(cur ^ 1);
      if (ks + 2 < NK) load_tiles((ks + 2) * 32);
    }
    __syncthreads();
    cur ^= 1;
  }

#pragma unroll
  for (int m = 0; m < 4; ++m) {
#pragma unroll
    for (int r = 0; r < 4; ++r) {
      int lr = wr * 64 + m * 16 + (lane >> 4) * 4 + r;
      if (lr < rows_valid) {
        size_t row = (size_t)(row_base + lr);
#pragma unroll
        for (int n = 0; n < 4; ++n) {
          out[row * HH + nb + wc * 64 + n * 16 + rl] = bf2f(f2bf(acc[m][n][r]));
        }
      }
    }
  }
}

extern "C" void kernel_launch(void* const* d_in, const int* in_sizes, int n_in,
                              void* d_out, int out_size, void* d_ws, size_t ws_size,
                              hipStream_t stream) {
  const float* x      = (const float*)d_in[0];
  const float* gup    = (const float*)d_in[1];
  const float* dp     = (const float*)d_in[2];
  const int*   counts = (const int*)d_in[3];
  float* out = (float*)d_out;
  short* h   = (short*)d_ws;  // bf16 h buffer: TT*II*2 = 46.1 MB

  const int MT_MAX = (TT + 127) / 128 + EE;   // 136
  const int NB1 = MT_MAX * (II / 64);         // 2992 (% 8 == 0)
  const int NB2 = MT_MAX * (HH / 128);        // 2176 (% 8 == 0)

  moe_gemm1<<<dim3(NB1), dim3(256), 0, stream>>>(x, gup, counts, h);
  moe_gemm2<<<dim3(NB2), dim3(256), 0, stream>>>(h, dp, counts, out);
}